// Round 9
// baseline (3945.078 us; speedup 1.0000x reference)
//
#include <hip/hip_runtime.h>
#include <cmath>

#define ZD    4096
#define HID   1024
#define G3    3072
#define DN    100
#define OD    100
#define BB    8
#define WW    512
#define ROWS  4096   // B*W

// Relaxed agent-scope (device-coherent) accessors: compile to global_load/store
// with sc0 sc1 -> bypass L1/L2, served at the coherence point (L3).
__device__ __forceinline__ void store_dc(float* p, float v) {
    __hip_atomic_store(p, v, __ATOMIC_RELAXED, __HIP_MEMORY_SCOPE_AGENT);
}

// ---------------- bf16 split helpers (RNE) ----------------
__device__ __forceinline__ unsigned short f2bf(float x) {
    unsigned u = __float_as_uint(x);
    u += 0x7FFFu + ((u >> 16) & 1u);
    return (unsigned short)(u >> 16);
}
__device__ __forceinline__ float bf2f(unsigned short h) {
    return __uint_as_float(((unsigned)h) << 16);
}

typedef short          s16x8 __attribute__((ext_vector_type(8)));
typedef unsigned short u16x8 __attribute__((ext_vector_type(8)));
typedef float          f32x4 __attribute__((ext_vector_type(4)));

// ---------------- W transpose + hi/lo split: S[K][N] fp32 -> T{h,l}[N][K] bf16 ----
__global__ __launch_bounds__(256) void split_T(
    const float* __restrict__ S, unsigned short* __restrict__ Th,
    unsigned short* __restrict__ Tl, int K, int N)
{
    __shared__ float ts[32][33];
    const int tx = threadIdx.x & 31;
    const int ty = threadIdx.x >> 5;     // 0..7
    const int n0 = blockIdx.x << 5;
    const int k0 = blockIdx.y << 5;
    #pragma unroll
    for (int i = 0; i < 4; ++i)
        ts[ty + (i << 3)][tx] = S[(size_t)(k0 + ty + (i << 3)) * N + n0 + tx];
    __syncthreads();
    #pragma unroll
    for (int i = 0; i < 4; ++i) {
        const int nrow = ty + (i << 3);
        const float v = ts[tx][nrow];                // = S[k0+tx][n0+nrow]
        const unsigned short h = f2bf(v);
        const size_t o = (size_t)(n0 + nrow) * K + k0 + tx;
        Th[o] = h;
        Tl[o] = f2bf(v - bf2f(h));
    }
}

// ---------------- MFMA GEMM: C[M,N] = A[M,K](f32) @ B (as BT{h,l}[N][K] bf16) + bias
// 128x128 tile, BK=32, 4 waves x (64x64 via 4x4 of 16x16x32 bf16 MFMA).
// fp32 emulated as hi*hi + hi*lo + lo*hi (lo*lo ~2^-18 rel, dropped).
// A split to hi/lo bf16 on the fly during LDS staging.
#define LP 56

__global__ __launch_bounds__(256) void gemm_bf16x3(
    const float* __restrict__ A,
    const unsigned short* __restrict__ BTh,
    const unsigned short* __restrict__ BTl,
    const float* __restrict__ bias,
    float* __restrict__ C,
    int M, int N, int K)
{
    __shared__ __align__(16) unsigned short Ah[128][LP];
    __shared__ __align__(16) unsigned short Al[128][LP];
    __shared__ __align__(16) unsigned short Bh[128][LP];
    __shared__ __align__(16) unsigned short Bl[128][LP];

    const int tid  = threadIdx.x;
    const int lane = tid & 63;
    const int wid  = tid >> 6;
    const int wm   = (wid >> 1) << 6;    // wave row origin: 0 / 64
    const int wn   = (wid & 1) << 6;     // wave col origin: 0 / 64
    const int l16  = lane & 15;
    const int gq   = lane >> 4;          // k-group 0..3
    const int bn0  = blockIdx.x << 7;
    const int bm0  = blockIdx.y << 7;

    f32x4 acc[4][4];
    #pragma unroll
    for (int i = 0; i < 4; ++i)
        #pragma unroll
        for (int j = 0; j < 4; ++j)
            acc[i][j] = (f32x4){0.f, 0.f, 0.f, 0.f};

    const int r0 = tid >> 2;             // staging row (iter 0): 0..63
    const int c8 = (tid & 3) << 3;       // elem offset 0/8/16/24

    for (int k0 = 0; k0 < K; k0 += 32) {
        __syncthreads();                 // prev iter's frag reads done before overwrite
        #pragma unroll
        for (int it = 0; it < 2; ++it) {
            const int r = r0 + (it << 6);
            // A: fp32 tile row -> hi/lo bf16
            const float* ap = A + (size_t)(bm0 + r) * K + k0 + c8;
            const float4 f0 = *(const float4*)ap;
            const float4 f1 = *(const float4*)(ap + 4);
            const float fv[8] = {f0.x, f0.y, f0.z, f0.w, f1.x, f1.y, f1.z, f1.w};
            u16x8 vh, vl;
            #pragma unroll
            for (int j = 0; j < 8; ++j) {
                const unsigned short h = f2bf(fv[j]);
                vh[j] = h;
                vl[j] = f2bf(fv[j] - bf2f(h));
            }
            *(u16x8*)&Ah[r][c8] = vh;
            *(u16x8*)&Al[r][c8] = vl;
            // B: pre-split bf16, direct copy
            const size_t boff = (size_t)(bn0 + r) * K + k0 + c8;
            *(u16x8*)&Bh[r][c8] = *(const u16x8*)(BTh + boff);
            *(u16x8*)&Bl[r][c8] = *(const u16x8*)(BTl + boff);
        }
        __syncthreads();

        s16x8 afh[4], afl[4];
        #pragma unroll
        for (int mi = 0; mi < 4; ++mi) {
            afh[mi] = *(const s16x8*)&Ah[wm + (mi << 4) + l16][gq << 3];
            afl[mi] = *(const s16x8*)&Al[wm + (mi << 4) + l16][gq << 3];
        }
        #pragma unroll
        for (int ni = 0; ni < 4; ++ni) {
            const s16x8 bfh = *(const s16x8*)&Bh[wn + (ni << 4) + l16][gq << 3];
            const s16x8 bfl = *(const s16x8*)&Bl[wn + (ni << 4) + l16][gq << 3];
            #pragma unroll
            for (int mi = 0; mi < 4; ++mi) {
                acc[mi][ni] = __builtin_amdgcn_mfma_f32_16x16x32_bf16(afh[mi], bfh, acc[mi][ni], 0, 0, 0);
                acc[mi][ni] = __builtin_amdgcn_mfma_f32_16x16x32_bf16(afh[mi], bfl, acc[mi][ni], 0, 0, 0);
                acc[mi][ni] = __builtin_amdgcn_mfma_f32_16x16x32_bf16(afl[mi], bfh, acc[mi][ni], 0, 0, 0);
            }
        }
    }

    // epilogue: C/D frag row=(l>>4)*4+r, col=l&15 (m89-verified)
    #pragma unroll
    for (int ni = 0; ni < 4; ++ni) {
        const int col = bn0 + wn + (ni << 4) + l16;
        const float bv = bias[col];
        #pragma unroll
        for (int mi = 0; mi < 4; ++mi) {
            const int rowb = bm0 + wm + (mi << 4) + (gq << 2);
            float* cp = C + (size_t)rowb * N + col;
            #pragma unroll
            for (int r = 0; r < 4; ++r)
                cp[(size_t)r * N] = acc[mi][ni][r] + bv;
        }
    }
}

// ---------------- fp32 GEMM (fallback path if workspace too small) ----------------
#define BM 64
#define BN 128
#define BK 16

__global__ __launch_bounds__(256) void gemm_f32(
    const float* __restrict__ A, const float* __restrict__ B,
    const float* __restrict__ bias, float* __restrict__ C,
    int M, int N, int K)
{
    __shared__ __align__(16) float As[BK][BM + 4];
    __shared__ __align__(16) float Bs[BK][BN + 4];
    const int tid = threadIdx.x;
    const int tx = tid & 15;
    const int ty = tid >> 4;
    const int bm0 = blockIdx.y * BM;
    const int bn0 = blockIdx.x * BN;

    float acc[4][8] = {};

    for (int k0 = 0; k0 < K; k0 += BK) {
        {
            const int mr = tid >> 2;
            const int kc = (tid & 3) << 2;
            float4 av = *(const float4*)(A + (size_t)(bm0 + mr) * K + k0 + kc);
            As[kc + 0][mr] = av.x;
            As[kc + 1][mr] = av.y;
            As[kc + 2][mr] = av.z;
            As[kc + 3][mr] = av.w;
        }
        #pragma unroll
        for (int i = 0; i < 2; ++i) {
            const int v = tid + (i << 8);
            const int kr = v >> 5;
            const int nc = (v & 31) << 2;
            *(float4*)&Bs[kr][nc] =
                *(const float4*)(B + (size_t)(k0 + kr) * N + bn0 + nc);
        }
        __syncthreads();
        #pragma unroll
        for (int kk = 0; kk < BK; ++kk) {
            float4 a  = *(const float4*)&As[kk][tx << 2];
            float4 b0 = *(const float4*)&Bs[kk][ty << 3];
            float4 b1 = *(const float4*)&Bs[kk][(ty << 3) + 4];
            const float av[4] = {a.x, a.y, a.z, a.w};
            const float bv[8] = {b0.x, b0.y, b0.z, b0.w, b1.x, b1.y, b1.z, b1.w};
            #pragma unroll
            for (int i = 0; i < 4; ++i)
                #pragma unroll
                for (int j = 0; j < 8; ++j)
                    acc[i][j] = fmaf(av[i], bv[j], acc[i][j]);
        }
        __syncthreads();
    }

    #pragma unroll
    for (int i = 0; i < 4; ++i) {
        const int row = bm0 + (tx << 2) + i;
        float* crow = C + (size_t)row * N + bn0 + (ty << 3);
        const float* brow = bias + bn0 + (ty << 3);
        float4 o0 = make_float4(acc[i][0] + brow[0], acc[i][1] + brow[1],
                                acc[i][2] + brow[2], acc[i][3] + brow[3]);
        float4 o1 = make_float4(acc[i][4] + brow[4], acc[i][5] + brow[5],
                                acc[i][6] + brow[6], acc[i][7] + brow[7]);
        *(float4*)crow = o0;
        *(float4*)(crow + 4) = o1;
    }
}

// ---------------- persistent GRU recurrence ----------------
// 256 blocks x 256 threads. Wave wv of block g owns hidden unit nh = g*4+wv;
// its 3 gate columns of W_hh are register-resident. h rotates through WW+1
// slots: slot t+1 written once (sc0 sc1 write-through), read once at step t+1
// with plain cached float4 loads (write-once/read-once slots; no stale copy).
//
// Barrier v3 (R4 + rotating dual detectors):
//  - arrival: block g STORES flag[g]=t+1 (no RMW chains).
//  - detect: blocks (t&255) and (t&255)+128 poll the 256 flags (wave 0 only,
//    64 lanes x 4 loads). ROTATION kills R4's systematic straggler: the
//    detect+release duty (~0.5-1us of serial work before the block's next
//    step) moved block 0's arrival late EVERY step, and the barrier waits for
//    the slowest block. Rotating spreads it to 2/256 of steps per block.
//    DUAL detectors: both write the same idempotent release values; consumers
//    see whichever lands first -> poll-phase jitter roughly halved.
//  - release: detector's 32 lanes store 32 release lines in ONE instruction.
//  - consumers: each wave polls its own release line (8 blocks/line, proven
//    contention-safe rate), no trailing __syncthreads (staging barrier
//    re-aligns; no hs access in between).
// Visibility: mid __syncthreads drains vmcnt(0) -> h stores at L3 before the
// flag store; release implies all flags implies all h. Monotonic epochs, no
// reset, skew <= 1 step, deadlock-free.
__global__ __launch_bounds__(256) void recur_kernel(
    const float* __restrict__ GI, const float* __restrict__ Whh,
    const float* __restrict__ bhh, float* __restrict__ Hm,
    unsigned* __restrict__ bar)
{
    __shared__ __align__(16) float hs[BB][HID];
    const int tid = threadIdx.x;
    const int lane = tid & 63;
    const int wv = tid >> 6;
    const int nh = blockIdx.x * 4 + wv;
    unsigned* rel = bar + 2048 + ((blockIdx.x & 31) << 5);   // 8 blocks / release line

    float wr0[16], wr1[16], wr2[16];
    #pragma unroll
    for (int j = 0; j < 4; ++j)
        #pragma unroll
        for (int q = 0; q < 4; ++q) {
            const int k = (j << 8) + (lane << 2) + q;
            const float* wrow = Whh + (size_t)k * G3;
            wr0[(j << 2) + q] = wrow[nh];
            wr1[(j << 2) + q] = wrow[HID + nh];
            wr2[(j << 2) + q] = wrow[2 * HID + nh];
        }
    const float bh0 = bhh[nh];
    const float bh1 = bhh[HID + nh];
    const float bh2 = bhh[2 * HID + nh];

    // prefetch gi for t=0 (lanes 0..7 = batch index)
    float gi_r = 0.f, gi_u = 0.f, gi_n = 0.f;
    if (lane < 8) {
        const float* gp = GI + ((size_t)lane * WW + 0) * G3;
        gi_r = gp[nh];
        gi_u = gp[HID + nh];
        gi_n = gp[2 * HID + nh];
    }

    for (int t = 0; t < WW; ++t) {
        // stage h_{t-1} (slot t) into LDS: plain cached float4 loads
        {
            const float4* hp = (const float4*)(Hm + (size_t)t * (BB * HID));
            float4* hd = (float4*)hs;
            #pragma unroll
            for (int i = 0; i < 8; ++i)
                hd[tid + (i << 8)] = hp[tid + (i << 8)];
        }
        // prefetch gi for t+1 (h-independent): latency hides under this step
        float gn_r = 0.f, gn_u = 0.f, gn_n = 0.f;
        if (lane < 8 && t + 1 < WW) {
            const float* gp = GI + ((size_t)lane * WW + (t + 1)) * G3;
            gn_r = gp[nh];
            gn_u = gp[HID + nh];
            gn_n = gp[2 * HID + nh];
        }
        __syncthreads();

        float s0 = 0.f, s1 = 0.f, s2 = 0.f;
        #pragma unroll
        for (int b = 0; b < BB; ++b) {
            const float4* hb = (const float4*)&hs[b][0];
            float p0 = 0.f, p1 = 0.f, p2 = 0.f;
            #pragma unroll
            for (int j = 0; j < 4; ++j) {
                float4 h4 = hb[(j << 6) + lane];
                const float hv[4] = {h4.x, h4.y, h4.z, h4.w};
                #pragma unroll
                for (int q = 0; q < 4; ++q) {
                    p0 = fmaf(hv[q], wr0[(j << 2) + q], p0);
                    p1 = fmaf(hv[q], wr1[(j << 2) + q], p1);
                    p2 = fmaf(hv[q], wr2[(j << 2) + q], p2);
                }
            }
            #pragma unroll
            for (int m = 32; m >= 1; m >>= 1) {
                p0 += __shfl_xor(p0, m, 64);
                p1 += __shfl_xor(p1, m, 64);
                p2 += __shfl_xor(p2, m, 64);
            }
            if (lane == b) { s0 = p0; s1 = p1; s2 = p2; }
        }
        // lanes 0..7 apply GRU update for (batch=lane, unit=nh); write-through to L3
        if (lane < 8) {
            const float hold = hs[lane][nh];
            const float r = 1.f / (1.f + expf(-(gi_r + s0 + bh0)));
            const float u = 1.f / (1.f + expf(-(gi_u + s1 + bh1)));
            const float n = tanhf(gi_n + r * (s2 + bh2));
            const float hnew = (1.f - u) * n + u * hold;
            store_dc(Hm + (size_t)(t + 1) * (BB * HID) + lane * HID + nh, hnew);
        }
        __syncthreads();   // s_waitcnt vmcnt(0): h stores at L3; last hs-read point

        if (t < WW - 1) {
            const unsigned want = (unsigned)(t + 1);
            if (tid == 0)
                __hip_atomic_store(bar + blockIdx.x, want,
                                   __ATOMIC_RELAXED, __HIP_MEMORY_SCOPE_AGENT);
            const unsigned root  = (unsigned)t & 255u;
            const unsigned root2 = (root + 128u) & 255u;
            if ((blockIdx.x == root || blockIdx.x == root2) && wv == 0) {
                // rotating detector: sole pollers of the 256 arrival flags
                for (;;) {
                    unsigned v0 = __hip_atomic_load(bar + lane,       __ATOMIC_RELAXED, __HIP_MEMORY_SCOPE_AGENT);
                    unsigned v1 = __hip_atomic_load(bar + lane + 64,  __ATOMIC_RELAXED, __HIP_MEMORY_SCOPE_AGENT);
                    unsigned v2 = __hip_atomic_load(bar + lane + 128, __ATOMIC_RELAXED, __HIP_MEMORY_SCOPE_AGENT);
                    unsigned v3 = __hip_atomic_load(bar + lane + 192, __ATOMIC_RELAXED, __HIP_MEMORY_SCOPE_AGENT);
                    unsigned mn = min(min(v0, v1), min(v2, v3));
                    if (__all(mn >= want)) break;
                }
                if (lane < 32)
                    __hip_atomic_store(bar + 2048 + (lane << 5), want,
                                       __ATOMIC_RELAXED, __HIP_MEMORY_SCOPE_AGENT);
            } else {
                while (__hip_atomic_load(rel, __ATOMIC_RELAXED,
                                         __HIP_MEMORY_SCOPE_AGENT) < want)
                    __builtin_amdgcn_s_sleep(1);
            }
            // no trailing __syncthreads: staging barrier re-aligns the block
        }
        gi_r = gn_r; gi_u = gn_u; gi_n = gn_n;
    }
}

// ---------------- dense + heads + reparameterized sample ----------------
__global__ __launch_bounds__(128) void head_kernel(
    const float* __restrict__ Hall, const float* __restrict__ Wd,
    const float* __restrict__ bd, const float* __restrict__ Wmu,
    const float* __restrict__ bmu, const float* __restrict__ Wsg,
    const float* __restrict__ bsg, const float* __restrict__ noise,
    float* __restrict__ out)
{
    const int blk = blockIdx.x;
    const int b = blk >> 7;
    const int t0 = (blk & 127) << 2;
    __shared__ __align__(16) float hsh[4][HID];
    __shared__ float dsh[4][DN];
    const int tid = threadIdx.x;

    #pragma unroll
    for (int rr = 0; rr < 4; ++rr) {
        const float4* hp = (const float4*)(Hall + (size_t)(t0 + rr) * (BB * HID) + (size_t)b * HID);
        ((float4*)hsh[rr])[tid] = hp[tid];
        ((float4*)hsh[rr])[tid + 128] = hp[tid + 128];
    }
    __syncthreads();

    if (tid < DN) {
        float a0 = bd[tid], a1 = bd[tid], a2 = bd[tid], a3 = bd[tid];
        for (int k = 0; k < HID; ++k) {
            const float wv = Wd[k * DN + tid];
            a0 = fmaf(hsh[0][k], wv, a0);
            a1 = fmaf(hsh[1][k], wv, a1);
            a2 = fmaf(hsh[2][k], wv, a2);
            a3 = fmaf(hsh[3][k], wv, a3);
        }
        dsh[0][tid] = a0; dsh[1][tid] = a1; dsh[2][tid] = a2; dsh[3][tid] = a3;
    }
    __syncthreads();

    if (tid < OD) {
        float mu[4], sg[4];
        #pragma unroll
        for (int rr = 0; rr < 4; ++rr) { mu[rr] = bmu[tid]; sg[rr] = bsg[tid]; }
        for (int i = 0; i < DN; ++i) {
            const float wm = Wmu[i * OD + tid];
            const float ws = Wsg[i * OD + tid];
            #pragma unroll
            for (int rr = 0; rr < 4; ++rr) {
                const float dv = dsh[rr][i];
                mu[rr] = fmaf(dv, wm, mu[rr]);
                sg[rr] = fmaf(dv, ws, sg[rr]);
            }
        }
        #pragma unroll
        for (int rr = 0; rr < 4; ++rr) {
            const float s = sg[rr];
            const float sp = (s > 20.f) ? s : log1pf(expf(s));
            const size_t oi = (size_t)b * (WW * OD) + (size_t)(t0 + rr) * OD + tid;
            out[oi] = mu[rr] + sp * noise[oi];
        }
    }
}

extern "C" void kernel_launch(void* const* d_in, const int* in_sizes, int n_in,
                              void* d_out, int out_size, void* d_ws, size_t ws_size,
                              hipStream_t stream)
{
    const float* z     = (const float*)d_in[0];
    const float* noise = (const float*)d_in[1];
    const float* W_L   = (const float*)d_in[2];
    const float* b_L   = (const float*)d_in[3];
    const float* W_ih  = (const float*)d_in[4];
    const float* b_ih  = (const float*)d_in[5];
    const float* W_hh  = (const float*)d_in[6];
    const float* b_hh  = (const float*)d_in[7];
    const float* W_d   = (const float*)d_in[8];
    const float* b_d   = (const float*)d_in[9];
    const float* W_mu  = (const float*)d_in[10];
    const float* b_mu  = (const float*)d_in[11];
    const float* W_sg  = (const float*)d_in[12];
    const float* b_sg  = (const float*)d_in[13];
    float* out = (float*)d_out;

    float* X    = (float*)d_ws;                      // 64MB fp32
    float* GIb  = X + (size_t)ROWS * ZD;             // 48MB fp32
    float* Hm   = GIb + (size_t)ROWS * G3;           // (512+1)*8192 fp32
    unsigned* bar = (unsigned*)(Hm + (size_t)(WW + 1) * (BB * HID));  // 16KB: flags[256] + release lines @ +2048dw
    unsigned short* WTh = (unsigned short*)((char*)bar + 16384);      // 32MB
    unsigned short* WTl = WTh + (size_t)ZD * ZD;                      // 32MB

    const size_t NEED = (size_t)ROWS * ZD * 4 + (size_t)ROWS * G3 * 4
                      + (size_t)(WW + 1) * (BB * HID) * 4 + 16384
                      + 2 * (size_t)ZD * ZD * 2;

    hipMemsetAsync(Hm, 0, (size_t)(BB * HID) * sizeof(float), stream);
    hipMemsetAsync(bar, 0, 16384, stream);

    if (ws_size >= NEED) {
        // MFMA path: bf16x3 split-precision GEMMs on the matrix cores.
        split_T<<<dim3(ZD / 32, ZD / 32), 256, 0, stream>>>(W_L, WTh, WTl, ZD, ZD);
        gemm_bf16x3<<<dim3(ZD / 128, ROWS / 128), 256, 0, stream>>>(
            z, WTh, WTl, b_L, X, ROWS, ZD, ZD);
        split_T<<<dim3(G3 / 32, ZD / 32), 256, 0, stream>>>(W_ih, WTh, WTl, ZD, G3);
        gemm_bf16x3<<<dim3(G3 / 128, ROWS / 128), 256, 0, stream>>>(
            X, WTh, WTl, b_ih, GIb, ROWS, G3, ZD);
    } else {
        // fallback: proven fp32 vector-ALU GEMMs
        gemm_f32<<<dim3(ZD / BN, ROWS / BM), 256, 0, stream>>>(z, W_L, b_L, X, ROWS, ZD, ZD);
        gemm_f32<<<dim3(G3 / BN, ROWS / BM), 256, 0, stream>>>(X, W_ih, b_ih, GIb, ROWS, G3, ZD);
    }

    // 256 compute blocks; detector role rotates over blocks (t&255, +128)
    void* args[] = { (void*)&GIb, (void*)&W_hh, (void*)&b_hh, (void*)&Hm, (void*)&bar };
    hipLaunchCooperativeKernel((void*)recur_kernel, dim3(HID / 4), dim3(256), args, 0, stream);

    head_kernel<<<dim3(ROWS / 4), 128, 0, stream>>>(Hm + BB * HID, W_d, b_d, W_mu, b_mu, W_sg, b_sg, noise, out);
}

// Round 10
// 3852.748 us; speedup vs baseline: 1.0240x; 1.0240x over previous
//
#include <hip/hip_runtime.h>
#include <cmath>

#define ZD    4096
#define HID   1024
#define G3    3072
#define DN    100
#define OD    100
#define BB    8
#define WW    512
#define ROWS  4096   // B*W

// Relaxed agent-scope (device-coherent) accessors: compile to global_load/store
// with sc0 sc1 -> bypass L1/L2, served at the coherence point (L3).
__device__ __forceinline__ void store_dc(float* p, float v) {
    __hip_atomic_store(p, v, __ATOMIC_RELAXED, __HIP_MEMORY_SCOPE_AGENT);
}

// ---------------- bf16 split helpers (RNE) ----------------
__device__ __forceinline__ unsigned short f2bf(float x) {
    unsigned u = __float_as_uint(x);
    u += 0x7FFFu + ((u >> 16) & 1u);
    return (unsigned short)(u >> 16);
}
__device__ __forceinline__ float bf2f(unsigned short h) {
    return __uint_as_float(((unsigned)h) << 16);
}

typedef short          s16x8 __attribute__((ext_vector_type(8)));
typedef unsigned short u16x8 __attribute__((ext_vector_type(8)));
typedef float          f32x4 __attribute__((ext_vector_type(4)));

// ---------------- W transpose + hi/lo split: S[K][N] fp32 -> T{h,l}[N][K] bf16 ----
__global__ __launch_bounds__(256) void split_T(
    const float* __restrict__ S, unsigned short* __restrict__ Th,
    unsigned short* __restrict__ Tl, int K, int N)
{
    __shared__ float ts[32][33];
    const int tx = threadIdx.x & 31;
    const int ty = threadIdx.x >> 5;     // 0..7
    const int n0 = blockIdx.x << 5;
    const int k0 = blockIdx.y << 5;
    #pragma unroll
    for (int i = 0; i < 4; ++i)
        ts[ty + (i << 3)][tx] = S[(size_t)(k0 + ty + (i << 3)) * N + n0 + tx];
    __syncthreads();
    #pragma unroll
    for (int i = 0; i < 4; ++i) {
        const int nrow = ty + (i << 3);
        const float v = ts[tx][nrow];                // = S[k0+tx][n0+nrow]
        const unsigned short h = f2bf(v);
        const size_t o = (size_t)(n0 + nrow) * K + k0 + tx;
        Th[o] = h;
        Tl[o] = f2bf(v - bf2f(h));
    }
}

// ---------------- MFMA GEMM #1: A fp32 (on-the-fly split), C written SPLIT ----
// C = A[M,K](f32) @ (BT{h,l}[N][K]) + bias -> Ch/Cl bf16 pair.
// Identical to the R1-R5 proven gemm_bf16x3 except the epilogue: instead of
// storing fp32 v, it stores {f2bf(v), f2bf(v - bf2f(f2bf(v)))} -- the exact
// ops gemm2's stager applied to the fp32 value in R5, so numerics are
// bit-identical while gemm2's K-loop split work disappears.
#define LP 56

__global__ __launch_bounds__(256) void gemm_bf16x3_ws(
    const float* __restrict__ A,
    const unsigned short* __restrict__ BTh,
    const unsigned short* __restrict__ BTl,
    const float* __restrict__ bias,
    unsigned short* __restrict__ Ch,
    unsigned short* __restrict__ Cl,
    int M, int N, int K)
{
    __shared__ __align__(16) unsigned short Ah[128][LP];
    __shared__ __align__(16) unsigned short Al[128][LP];
    __shared__ __align__(16) unsigned short Bh[128][LP];
    __shared__ __align__(16) unsigned short Bl[128][LP];

    const int tid  = threadIdx.x;
    const int lane = tid & 63;
    const int wid  = tid >> 6;
    const int wm   = (wid >> 1) << 6;
    const int wn   = (wid & 1) << 6;
    const int l16  = lane & 15;
    const int gq   = lane >> 4;
    const int bn0  = blockIdx.x << 7;
    const int bm0  = blockIdx.y << 7;

    f32x4 acc[4][4];
    #pragma unroll
    for (int i = 0; i < 4; ++i)
        #pragma unroll
        for (int j = 0; j < 4; ++j)
            acc[i][j] = (f32x4){0.f, 0.f, 0.f, 0.f};

    const int r0 = tid >> 2;
    const int c8 = (tid & 3) << 3;

    for (int k0 = 0; k0 < K; k0 += 32) {
        __syncthreads();
        #pragma unroll
        for (int it = 0; it < 2; ++it) {
            const int r = r0 + (it << 6);
            const float* ap = A + (size_t)(bm0 + r) * K + k0 + c8;
            const float4 f0 = *(const float4*)ap;
            const float4 f1 = *(const float4*)(ap + 4);
            const float fv[8] = {f0.x, f0.y, f0.z, f0.w, f1.x, f1.y, f1.z, f1.w};
            u16x8 vh, vl;
            #pragma unroll
            for (int j = 0; j < 8; ++j) {
                const unsigned short h = f2bf(fv[j]);
                vh[j] = h;
                vl[j] = f2bf(fv[j] - bf2f(h));
            }
            *(u16x8*)&Ah[r][c8] = vh;
            *(u16x8*)&Al[r][c8] = vl;
            const size_t boff = (size_t)(bn0 + r) * K + k0 + c8;
            *(u16x8*)&Bh[r][c8] = *(const u16x8*)(BTh + boff);
            *(u16x8*)&Bl[r][c8] = *(const u16x8*)(BTl + boff);
        }
        __syncthreads();

        s16x8 afh[4], afl[4];
        #pragma unroll
        for (int mi = 0; mi < 4; ++mi) {
            afh[mi] = *(const s16x8*)&Ah[wm + (mi << 4) + l16][gq << 3];
            afl[mi] = *(const s16x8*)&Al[wm + (mi << 4) + l16][gq << 3];
        }
        #pragma unroll
        for (int ni = 0; ni < 4; ++ni) {
            const s16x8 bfh = *(const s16x8*)&Bh[wn + (ni << 4) + l16][gq << 3];
            const s16x8 bfl = *(const s16x8*)&Bl[wn + (ni << 4) + l16][gq << 3];
            #pragma unroll
            for (int mi = 0; mi < 4; ++mi) {
                acc[mi][ni] = __builtin_amdgcn_mfma_f32_16x16x32_bf16(afh[mi], bfh, acc[mi][ni], 0, 0, 0);
                acc[mi][ni] = __builtin_amdgcn_mfma_f32_16x16x32_bf16(afh[mi], bfl, acc[mi][ni], 0, 0, 0);
                acc[mi][ni] = __builtin_amdgcn_mfma_f32_16x16x32_bf16(afl[mi], bfh, acc[mi][ni], 0, 0, 0);
            }
        }
    }

    // epilogue: C/D frag row=(l>>4)*4+r, col=l&15 (m89-verified); split write
    #pragma unroll
    for (int ni = 0; ni < 4; ++ni) {
        const int col = bn0 + wn + (ni << 4) + l16;
        const float bv = bias[col];
        #pragma unroll
        for (int mi = 0; mi < 4; ++mi) {
            const int rowb = bm0 + wm + (mi << 4) + (gq << 2);
            #pragma unroll
            for (int r = 0; r < 4; ++r) {
                const float v = acc[mi][ni][r] + bv;
                const size_t o = (size_t)(rowb + r) * N + col;
                const unsigned short h = f2bf(v);
                Ch[o] = h;
                Cl[o] = f2bf(v - bf2f(h));
            }
        }
    }
}

// ---------------- MFMA GEMM #2: A PRE-SPLIT (straight copies), C fp32 ----
// C = (Ah+Al)[M,K] @ (BT{h,l}[N][K]) + bias. Identical to R1-R5 gemm_bf16x3
// except A-staging is two u16x8 copies (no fp32->bf16 VALU in the K-loop).
__global__ __launch_bounds__(256) void gemm_bf16x3_pre(
    const unsigned short* __restrict__ ATh,
    const unsigned short* __restrict__ ATl,
    const unsigned short* __restrict__ BTh,
    const unsigned short* __restrict__ BTl,
    const float* __restrict__ bias,
    float* __restrict__ C,
    int M, int N, int K)
{
    __shared__ __align__(16) unsigned short Ah[128][LP];
    __shared__ __align__(16) unsigned short Al[128][LP];
    __shared__ __align__(16) unsigned short Bh[128][LP];
    __shared__ __align__(16) unsigned short Bl[128][LP];

    const int tid  = threadIdx.x;
    const int lane = tid & 63;
    const int wid  = tid >> 6;
    const int wm   = (wid >> 1) << 6;
    const int wn   = (wid & 1) << 6;
    const int l16  = lane & 15;
    const int gq   = lane >> 4;
    const int bn0  = blockIdx.x << 7;
    const int bm0  = blockIdx.y << 7;

    f32x4 acc[4][4];
    #pragma unroll
    for (int i = 0; i < 4; ++i)
        #pragma unroll
        for (int j = 0; j < 4; ++j)
            acc[i][j] = (f32x4){0.f, 0.f, 0.f, 0.f};

    const int r0 = tid >> 2;
    const int c8 = (tid & 3) << 3;

    for (int k0 = 0; k0 < K; k0 += 32) {
        __syncthreads();
        #pragma unroll
        for (int it = 0; it < 2; ++it) {
            const int r = r0 + (it << 6);
            const size_t aoff = (size_t)(bm0 + r) * K + k0 + c8;
            const size_t boff = (size_t)(bn0 + r) * K + k0 + c8;
            *(u16x8*)&Ah[r][c8] = *(const u16x8*)(ATh + aoff);
            *(u16x8*)&Al[r][c8] = *(const u16x8*)(ATl + aoff);
            *(u16x8*)&Bh[r][c8] = *(const u16x8*)(BTh + boff);
            *(u16x8*)&Bl[r][c8] = *(const u16x8*)(BTl + boff);
        }
        __syncthreads();

        s16x8 afh[4], afl[4];
        #pragma unroll
        for (int mi = 0; mi < 4; ++mi) {
            afh[mi] = *(const s16x8*)&Ah[wm + (mi << 4) + l16][gq << 3];
            afl[mi] = *(const s16x8*)&Al[wm + (mi << 4) + l16][gq << 3];
        }
        #pragma unroll
        for (int ni = 0; ni < 4; ++ni) {
            const s16x8 bfh = *(const s16x8*)&Bh[wn + (ni << 4) + l16][gq << 3];
            const s16x8 bfl = *(const s16x8*)&Bl[wn + (ni << 4) + l16][gq << 3];
            #pragma unroll
            for (int mi = 0; mi < 4; ++mi) {
                acc[mi][ni] = __builtin_amdgcn_mfma_f32_16x16x32_bf16(afh[mi], bfh, acc[mi][ni], 0, 0, 0);
                acc[mi][ni] = __builtin_amdgcn_mfma_f32_16x16x32_bf16(afh[mi], bfl, acc[mi][ni], 0, 0, 0);
                acc[mi][ni] = __builtin_amdgcn_mfma_f32_16x16x32_bf16(afl[mi], bfh, acc[mi][ni], 0, 0, 0);
            }
        }
    }

    // epilogue: C/D frag row=(l>>4)*4+r, col=l&15 (m89-verified)
    #pragma unroll
    for (int ni = 0; ni < 4; ++ni) {
        const int col = bn0 + wn + (ni << 4) + l16;
        const float bv = bias[col];
        #pragma unroll
        for (int mi = 0; mi < 4; ++mi) {
            const int rowb = bm0 + wm + (mi << 4) + (gq << 2);
            float* cp = C + (size_t)rowb * N + col;
            #pragma unroll
            for (int r = 0; r < 4; ++r)
                cp[(size_t)r * N] = acc[mi][ni][r] + bv;
        }
    }
}

// ---------------- fp32 GEMM (fallback path if workspace too small) ----------------
#define BM 64
#define BN 128
#define BK 16

__global__ __launch_bounds__(256) void gemm_f32(
    const float* __restrict__ A, const float* __restrict__ B,
    const float* __restrict__ bias, float* __restrict__ C,
    int M, int N, int K)
{
    __shared__ __align__(16) float As[BK][BM + 4];
    __shared__ __align__(16) float Bs[BK][BN + 4];
    const int tid = threadIdx.x;
    const int tx = tid & 15;
    const int ty = tid >> 4;
    const int bm0 = blockIdx.y * BM;
    const int bn0 = blockIdx.x * BN;

    float acc[4][8] = {};

    for (int k0 = 0; k0 < K; k0 += BK) {
        {
            const int mr = tid >> 2;
            const int kc = (tid & 3) << 2;
            float4 av = *(const float4*)(A + (size_t)(bm0 + mr) * K + k0 + kc);
            As[kc + 0][mr] = av.x;
            As[kc + 1][mr] = av.y;
            As[kc + 2][mr] = av.z;
            As[kc + 3][mr] = av.w;
        }
        #pragma unroll
        for (int i = 0; i < 2; ++i) {
            const int v = tid + (i << 8);
            const int kr = v >> 5;
            const int nc = (v & 31) << 2;
            *(float4*)&Bs[kr][nc] =
                *(const float4*)(B + (size_t)(k0 + kr) * N + bn0 + nc);
        }
        __syncthreads();
        #pragma unroll
        for (int kk = 0; kk < BK; ++kk) {
            float4 a  = *(const float4*)&As[kk][tx << 2];
            float4 b0 = *(const float4*)&Bs[kk][ty << 3];
            float4 b1 = *(const float4*)&Bs[kk][(ty << 3) + 4];
            const float av[4] = {a.x, a.y, a.z, a.w};
            const float bv[8] = {b0.x, b0.y, b0.z, b0.w, b1.x, b1.y, b1.z, b1.w};
            #pragma unroll
            for (int i = 0; i < 4; ++i)
                #pragma unroll
                for (int j = 0; j < 8; ++j)
                    acc[i][j] = fmaf(av[i], bv[j], acc[i][j]);
        }
        __syncthreads();
    }

    #pragma unroll
    for (int i = 0; i < 4; ++i) {
        const int row = bm0 + (tx << 2) + i;
        float* crow = C + (size_t)row * N + bn0 + (ty << 3);
        const float* brow = bias + bn0 + (ty << 3);
        float4 o0 = make_float4(acc[i][0] + brow[0], acc[i][1] + brow[1],
                                acc[i][2] + brow[2], acc[i][3] + brow[3]);
        float4 o1 = make_float4(acc[i][4] + brow[4], acc[i][5] + brow[5],
                                acc[i][6] + brow[6], acc[i][7] + brow[7]);
        *(float4*)crow = o0;
        *(float4*)(crow + 4) = o1;
    }
}

// ---------------- persistent GRU recurrence (unchanged from R5) ----------------
// 256 blocks x 256 threads. Wave wv of block g owns hidden unit nh = g*4+wv.
// Barrier: push-store arrivals, rotating dual detectors, parallel release
// fan-out, per-wave release poll. ~5.4us/step = sync-latency floor for this
// decomposition (tree/flat/root/rotating all within 2775+-25us).
__global__ __launch_bounds__(256) void recur_kernel(
    const float* __restrict__ GI, const float* __restrict__ Whh,
    const float* __restrict__ bhh, float* __restrict__ Hm,
    unsigned* __restrict__ bar)
{
    __shared__ __align__(16) float hs[BB][HID];
    const int tid = threadIdx.x;
    const int lane = tid & 63;
    const int wv = tid >> 6;
    const int nh = blockIdx.x * 4 + wv;
    unsigned* rel = bar + 2048 + ((blockIdx.x & 31) << 5);   // 8 blocks / release line

    float wr0[16], wr1[16], wr2[16];
    #pragma unroll
    for (int j = 0; j < 4; ++j)
        #pragma unroll
        for (int q = 0; q < 4; ++q) {
            const int k = (j << 8) + (lane << 2) + q;
            const float* wrow = Whh + (size_t)k * G3;
            wr0[(j << 2) + q] = wrow[nh];
            wr1[(j << 2) + q] = wrow[HID + nh];
            wr2[(j << 2) + q] = wrow[2 * HID + nh];
        }
    const float bh0 = bhh[nh];
    const float bh1 = bhh[HID + nh];
    const float bh2 = bhh[2 * HID + nh];

    // prefetch gi for t=0 (lanes 0..7 = batch index)
    float gi_r = 0.f, gi_u = 0.f, gi_n = 0.f;
    if (lane < 8) {
        const float* gp = GI + ((size_t)lane * WW + 0) * G3;
        gi_r = gp[nh];
        gi_u = gp[HID + nh];
        gi_n = gp[2 * HID + nh];
    }

    for (int t = 0; t < WW; ++t) {
        // stage h_{t-1} (slot t) into LDS: plain cached float4 loads
        {
            const float4* hp = (const float4*)(Hm + (size_t)t * (BB * HID));
            float4* hd = (float4*)hs;
            #pragma unroll
            for (int i = 0; i < 8; ++i)
                hd[tid + (i << 8)] = hp[tid + (i << 8)];
        }
        // prefetch gi for t+1 (h-independent): latency hides under this step
        float gn_r = 0.f, gn_u = 0.f, gn_n = 0.f;
        if (lane < 8 && t + 1 < WW) {
            const float* gp = GI + ((size_t)lane * WW + (t + 1)) * G3;
            gn_r = gp[nh];
            gn_u = gp[HID + nh];
            gn_n = gp[2 * HID + nh];
        }
        __syncthreads();

        float s0 = 0.f, s1 = 0.f, s2 = 0.f;
        #pragma unroll
        for (int b = 0; b < BB; ++b) {
            const float4* hb = (const float4*)&hs[b][0];
            float p0 = 0.f, p1 = 0.f, p2 = 0.f;
            #pragma unroll
            for (int j = 0; j < 4; ++j) {
                float4 h4 = hb[(j << 6) + lane];
                const float hv[4] = {h4.x, h4.y, h4.z, h4.w};
                #pragma unroll
                for (int q = 0; q < 4; ++q) {
                    p0 = fmaf(hv[q], wr0[(j << 2) + q], p0);
                    p1 = fmaf(hv[q], wr1[(j << 2) + q], p1);
                    p2 = fmaf(hv[q], wr2[(j << 2) + q], p2);
                }
            }
            #pragma unroll
            for (int m = 32; m >= 1; m >>= 1) {
                p0 += __shfl_xor(p0, m, 64);
                p1 += __shfl_xor(p1, m, 64);
                p2 += __shfl_xor(p2, m, 64);
            }
            if (lane == b) { s0 = p0; s1 = p1; s2 = p2; }
        }
        // lanes 0..7 apply GRU update for (batch=lane, unit=nh); write-through to L3
        if (lane < 8) {
            const float hold = hs[lane][nh];
            const float r = 1.f / (1.f + expf(-(gi_r + s0 + bh0)));
            const float u = 1.f / (1.f + expf(-(gi_u + s1 + bh1)));
            const float n = tanhf(gi_n + r * (s2 + bh2));
            const float hnew = (1.f - u) * n + u * hold;
            store_dc(Hm + (size_t)(t + 1) * (BB * HID) + lane * HID + nh, hnew);
        }
        __syncthreads();   // s_waitcnt vmcnt(0): h stores at L3; last hs-read point

        if (t < WW - 1) {
            const unsigned want = (unsigned)(t + 1);
            if (tid == 0)
                __hip_atomic_store(bar + blockIdx.x, want,
                                   __ATOMIC_RELAXED, __HIP_MEMORY_SCOPE_AGENT);
            const unsigned root  = (unsigned)t & 255u;
            const unsigned root2 = (root + 128u) & 255u;
            if ((blockIdx.x == root || blockIdx.x == root2) && wv == 0) {
                // rotating detector: sole pollers of the 256 arrival flags
                for (;;) {
                    unsigned v0 = __hip_atomic_load(bar + lane,       __ATOMIC_RELAXED, __HIP_MEMORY_SCOPE_AGENT);
                    unsigned v1 = __hip_atomic_load(bar + lane + 64,  __ATOMIC_RELAXED, __HIP_MEMORY_SCOPE_AGENT);
                    unsigned v2 = __hip_atomic_load(bar + lane + 128, __ATOMIC_RELAXED, __HIP_MEMORY_SCOPE_AGENT);
                    unsigned v3 = __hip_atomic_load(bar + lane + 192, __ATOMIC_RELAXED, __HIP_MEMORY_SCOPE_AGENT);
                    unsigned mn = min(min(v0, v1), min(v2, v3));
                    if (__all(mn >= want)) break;
                }
                if (lane < 32)
                    __hip_atomic_store(bar + 2048 + (lane << 5), want,
                                       __ATOMIC_RELAXED, __HIP_MEMORY_SCOPE_AGENT);
            } else {
                while (__hip_atomic_load(rel, __ATOMIC_RELAXED,
                                         __HIP_MEMORY_SCOPE_AGENT) < want)
                    __builtin_amdgcn_s_sleep(1);
            }
            // no trailing __syncthreads: staging barrier re-aligns the block
        }
        gi_r = gn_r; gi_u = gn_u; gi_n = gn_n;
    }
}

// ---------------- dense + heads + reparameterized sample ----------------
__global__ __launch_bounds__(128) void head_kernel(
    const float* __restrict__ Hall, const float* __restrict__ Wd,
    const float* __restrict__ bd, const float* __restrict__ Wmu,
    const float* __restrict__ bmu, const float* __restrict__ Wsg,
    const float* __restrict__ bsg, const float* __restrict__ noise,
    float* __restrict__ out)
{
    const int blk = blockIdx.x;
    const int b = blk >> 7;
    const int t0 = (blk & 127) << 2;
    __shared__ __align__(16) float hsh[4][HID];
    __shared__ float dsh[4][DN];
    const int tid = threadIdx.x;

    #pragma unroll
    for (int rr = 0; rr < 4; ++rr) {
        const float4* hp = (const float4*)(Hall + (size_t)(t0 + rr) * (BB * HID) + (size_t)b * HID);
        ((float4*)hsh[rr])[tid] = hp[tid];
        ((float4*)hsh[rr])[tid + 128] = hp[tid + 128];
    }
    __syncthreads();

    if (tid < DN) {
        float a0 = bd[tid], a1 = bd[tid], a2 = bd[tid], a3 = bd[tid];
        for (int k = 0; k < HID; ++k) {
            const float wv = Wd[k * DN + tid];
            a0 = fmaf(hsh[0][k], wv, a0);
            a1 = fmaf(hsh[1][k], wv, a1);
            a2 = fmaf(hsh[2][k], wv, a2);
            a3 = fmaf(hsh[3][k], wv, a3);
        }
        dsh[0][tid] = a0; dsh[1][tid] = a1; dsh[2][tid] = a2; dsh[3][tid] = a3;
    }
    __syncthreads();

    if (tid < OD) {
        float mu[4], sg[4];
        #pragma unroll
        for (int rr = 0; rr < 4; ++rr) { mu[rr] = bmu[tid]; sg[rr] = bsg[tid]; }
        for (int i = 0; i < DN; ++i) {
            const float wm = Wmu[i * OD + tid];
            const float ws = Wsg[i * OD + tid];
            #pragma unroll
            for (int rr = 0; rr < 4; ++rr) {
                const float dv = dsh[rr][i];
                mu[rr] = fmaf(dv, wm, mu[rr]);
                sg[rr] = fmaf(dv, ws, sg[rr]);
            }
        }
        #pragma unroll
        for (int rr = 0; rr < 4; ++rr) {
            const float s = sg[rr];
            const float sp = (s > 20.f) ? s : log1pf(expf(s));
            const size_t oi = (size_t)b * (WW * OD) + (size_t)(t0 + rr) * OD + tid;
            out[oi] = mu[rr] + sp * noise[oi];
        }
    }
}

extern "C" void kernel_launch(void* const* d_in, const int* in_sizes, int n_in,
                              void* d_out, int out_size, void* d_ws, size_t ws_size,
                              hipStream_t stream)
{
    const float* z     = (const float*)d_in[0];
    const float* noise = (const float*)d_in[1];
    const float* W_L   = (const float*)d_in[2];
    const float* b_L   = (const float*)d_in[3];
    const float* W_ih  = (const float*)d_in[4];
    const float* b_ih  = (const float*)d_in[5];
    const float* W_hh  = (const float*)d_in[6];
    const float* b_hh  = (const float*)d_in[7];
    const float* W_d   = (const float*)d_in[8];
    const float* b_d   = (const float*)d_in[9];
    const float* W_mu  = (const float*)d_in[10];
    const float* b_mu  = (const float*)d_in[11];
    const float* W_sg  = (const float*)d_in[12];
    const float* b_sg  = (const float*)d_in[13];
    float* out = (float*)d_out;

    // ---- R5's exact layout; the X slot (ROWS*ZD*4 bytes) now holds Xh+Xl
    // (2 * ROWS*ZD*2 bytes -- byte-identical footprint). NEED unchanged.
    unsigned short* Xh = (unsigned short*)d_ws;
    unsigned short* Xl = Xh + (size_t)ROWS * ZD;          // ends exactly where fp32 X ended
    float* GIb  = (float*)(Xl + (size_t)ROWS * ZD);       // same address as R5's GIb
    float* Hm   = GIb + (size_t)ROWS * G3;
    unsigned* bar = (unsigned*)(Hm + (size_t)(WW + 1) * (BB * HID));
    unsigned short* WTh = (unsigned short*)((char*)bar + 16384);
    unsigned short* WTl = WTh + (size_t)ZD * ZD;

    const size_t NEED = (size_t)ROWS * ZD * 4 + (size_t)ROWS * G3 * 4
                      + (size_t)(WW + 1) * (BB * HID) * 4 + 16384
                      + 2 * (size_t)ZD * ZD * 2;

    hipMemsetAsync(Hm, 0, (size_t)(BB * HID) * sizeof(float), stream);
    hipMemsetAsync(bar, 0, 16384, stream);

    if (ws_size >= NEED) {
        // MFMA path: bf16x3 split-precision GEMMs on the matrix cores.
        split_T<<<dim3(ZD / 32, ZD / 32), 256, 0, stream>>>(W_L, WTh, WTl, ZD, ZD);
        // gemm1: X = z @ W_L + b_L, epilogue writes split bf16 (Xh, Xl)
        gemm_bf16x3_ws<<<dim3(ZD / 128, ROWS / 128), 256, 0, stream>>>(
            z, WTh, WTl, b_L, Xh, Xl, ROWS, ZD, ZD);
        split_T<<<dim3(G3 / 32, ZD / 32), 256, 0, stream>>>(W_ih, WTh, WTl, ZD, G3);
        // gemm2: GI = X @ W_ih + b_ih, A pre-split -> straight u16x8 staging
        gemm_bf16x3_pre<<<dim3(G3 / 128, ROWS / 128), 256, 0, stream>>>(
            Xh, Xl, WTh, WTl, b_ih, GIb, ROWS, G3, ZD);
    } else {
        // fallback: proven fp32 vector-ALU GEMMs (X fp32 in the same first slot)
        float* Xf = (float*)d_ws;
        gemm_f32<<<dim3(ZD / BN, ROWS / BM), 256, 0, stream>>>(z, W_L, b_L, Xf, ROWS, ZD, ZD);
        gemm_f32<<<dim3(G3 / BN, ROWS / BM), 256, 0, stream>>>(Xf, W_ih, b_ih, GIb, ROWS, G3, ZD);
    }

    // sequential GRU scan (cooperative launch for co-residency)
    void* args[] = { (void*)&GIb, (void*)&W_hh, (void*)&b_hh, (void*)&Hm, (void*)&bar };
    hipLaunchCooperativeKernel((void*)recur_kernel, dim3(HID / 4), dim3(256), args, 0, stream);

    // dense + mu/sigma heads + sample (h_t lives in Hm slot t+1)
    head_kernel<<<dim3(ROWS / 4), 128, 0, stream>>>(Hm + BB * HID, W_d, b_d, W_mu, b_mu, W_sg, b_sg, noise, out);
}